// Round 18
// baseline (212.432 us; speedup 1.0000x reference)
//
#include <hip/hip_runtime.h>
#include <hip/hip_bf16.h>
#include <stdint.h>

#define BB 4
#define TT 2048
#define DD 1024
#define HH 16
#define DKK 64

typedef unsigned short u16;
typedef unsigned int u32;
typedef __bf16 bf16_t;
typedef bf16_t bf16x8 __attribute__((ext_vector_type(8)));
typedef float f32x4 __attribute__((ext_vector_type(4)));

#if __has_builtin(__builtin_amdgcn_exp2f)
#define EXPW(x) __builtin_amdgcn_exp2f(x)
#define QSCL 0.1803368801111244f  /* 0.125 * log2(e): exp done in base-2 domain */
#else
#define EXPW(x) __expf(x)
#define QSCL 0.125f
#endif

__device__ __forceinline__ float bf2f(u16 u) {
    u32 x = ((u32)u) << 16;
    float f;
    __builtin_memcpy(&f, &x, 4);
    return f;
}
__device__ __forceinline__ u16 f2bf(float f) {
    u32 x;
    __builtin_memcpy(&x, &f, 4);
    x += 0x7fffu + ((x >> 16) & 1u);  // RNE truncate (no NaN inputs here)
    return (u16)(x >> 16);
}
// NOTE: v_cvt_pk_bf16_f32 inline asm is BANNED: every NaN failure this session
// (r6, r7, r16) contained it; every kernel without it passed.

// async global->LDS, 16B per lane; l must be the WAVE-UNIFORM base (lane*16 added by HW)
__device__ __forceinline__ void gll16(const u16* g, u16* l) {
    __builtin_amdgcn_global_load_lds((const __attribute__((address_space(1))) u32*)g,
                                     (__attribute__((address_space(3))) u32*)l, 16, 0, 0);
}

// ---------------------------------------------------------------- casts (merged: 1 dispatch)
__global__ void cast_all(const float* __restrict__ x,
                         const float* __restrict__ w0, const float* __restrict__ w1,
                         const float* __restrict__ w2, const float* __restrict__ w3,
                         u16* __restrict__ outx, u16* __restrict__ outw, int nX, int nW) {
    const float* src;
    u16* dst;
    int n;
    if (blockIdx.y == 0) { src = x; dst = outx; n = nX; }
    else {
        src = (blockIdx.y == 1) ? w0 : (blockIdx.y == 2) ? w1 : (blockIdx.y == 3) ? w2 : w3;
        dst = outw + (size_t)(blockIdx.y - 1) * nW;
        n = nW;
    }
    int i = (blockIdx.x * blockDim.x + threadIdx.x) * 4;
    int stride = gridDim.x * blockDim.x * 4;
    for (; i < n; i += stride) {
        float4 v = *reinterpret_cast<const float4*>(src + i);
        uint2 pk;
        pk.x = (u32)f2bf(v.x) | ((u32)f2bf(v.y) << 16);
        pk.y = (u32)f2bf(v.z) | ((u32)f2bf(v.w) << 16);
        *reinterpret_cast<uint2*>(dst + i) = pk;
    }
}

// ---------------------------------------------------------------- GEMM core, BK=64
// C[m][n] = sum_k A[m][k] * W[n][k]  (TN), tiles 128x128, K-slab 64.
// Same 2-barrier schedule as the proven r11 loop (r12: ring/single-barrier
// REGRESSED), but 16 K-steps instead of 32 -> half the barrier/drain events
// per FLOP. LDS 32 KB (still >=4 blocks/CU; m132's cliff was 64 KB). Fragments
// loaded PER kc-HALF inside the loop so live regs stay ~8 frags (no spill).
__device__ __forceinline__ void gemm_128_mainloop(const u16* __restrict__ A,
                                                  const u16* __restrict__ W,
                                                  u16* As, u16* Bs,  // [128*64] each
                                                  int m0, int n0, f32x4 acc[4][4]) {
    const int tid = threadIdx.x;
    const int lane = tid & 63;
    const int wid = tid >> 6;
    const int wr = (wid >> 1) * 64, wc = (wid & 1) * 64;
    const int l15 = lane & 15, l4 = lane >> 4;

    const f32x4 z4 = {0.f, 0.f, 0.f, 0.f};
#pragma unroll
    for (int i = 0; i < 4; i++)
#pragma unroll
        for (int j = 0; j < 4; j++) acc[i][j] = z4;

    for (int k0 = 0; k0 < DD; k0 += 64) {
        __syncthreads();
        // stage A[128][64] + B[128][64]: 1024 chunks each, 4 chunks/thread each.
        // chunk id = iss*256 + tid = iss*256 + wid*64 + lane -> LDS base
        // (iss*256 + wid*64)*8 u16 is wave-uniform; row = id>>3, cc = id&7.
#pragma unroll
        for (int iss = 0; iss < 4; iss++) {
            int id = iss * 256 + tid;
            int r = id >> 3, cc = id & 7;
            gll16(A + (m0 + r) * DD + k0 + cc * 8, As + (iss * 256 + wid * 64) * 8);
            gll16(W + (n0 + r) * DD + k0 + cc * 8, Bs + (iss * 256 + wid * 64) * 8);
        }
        asm volatile("s_waitcnt vmcnt(0)" ::: "memory");
        __syncthreads();

#pragma unroll
        for (int kc = 0; kc < 2; kc++) {
            bf16x8 af[4], bfr[4];
#pragma unroll
            for (int mi = 0; mi < 4; mi++)
                af[mi] = *reinterpret_cast<const bf16x8*>(
                    As + (wr + mi * 16 + l15) * 64 + kc * 32 + l4 * 8);
#pragma unroll
            for (int ni = 0; ni < 4; ni++)
                bfr[ni] = *reinterpret_cast<const bf16x8*>(
                    Bs + (wc + ni * 16 + l15) * 64 + kc * 32 + l4 * 8);
#pragma unroll
            for (int mi = 0; mi < 4; mi++)
#pragma unroll
                for (int ni = 0; ni < 4; ni++)
                    acc[mi][ni] = __builtin_amdgcn_mfma_f32_16x16x32_bf16(
                        af[mi], bfr[ni], acc[mi][ni], 0, 0, 0);
        }
    }
}

// z=0: Q  -> [b][h][t][dk] bf16 ; z=1: K same ; z=2: V -> [b][h][dk][t] bf16 (transposed)
__global__ __launch_bounds__(256) void gemm_qkv(const u16* __restrict__ xb,
                                                const u16* __restrict__ wq,
                                                const u16* __restrict__ wk,
                                                const u16* __restrict__ wv,
                                                u16* __restrict__ Qo, u16* __restrict__ Ko,
                                                u16* __restrict__ Vto) {
    __shared__ u16 As[128 * 64];   // 16 KB
    __shared__ u16 Bs[128 * 64];   // 16 KB
    const int z = blockIdx.z;
    const u16* W = (z == 0) ? wq : (z == 1) ? wk : wv;
    u16* dst = (z == 0) ? Qo : (z == 1) ? Ko : Vto;
    const int m0 = blockIdx.x * 128, n0 = blockIdx.y * 128;

    f32x4 acc[4][4];
    gemm_128_mainloop(xb, W, As, Bs, m0, n0, acc);

    const int lane = threadIdx.x & 63, wid = threadIdx.x >> 6;
    const int wr = (wid >> 1) * 64, wc = (wid & 1) * 64;
    const int l15 = lane & 15, l4 = lane >> 4;
#pragma unroll
    for (int mi = 0; mi < 4; mi++)
#pragma unroll
        for (int ni = 0; ni < 4; ni++)
#pragma unroll
            for (int j = 0; j < 4; j++) {
                int m = m0 + wr + mi * 16 + l4 * 4 + j;  // token
                int n = n0 + wc + ni * 16 + l15;          // feature e = h*64+dk
                int b = m >> 11, t = m & (TT - 1);
                int h = n >> 6, dk = n & 63;
                u16 v = f2bf(acc[mi][ni][j]);
                if (z < 2)
                    dst[((b * HH + h) * TT + t) * DKK + dk] = v;
                else
                    dst[((b * HH + h) * DKK + dk) * TT + t] = v;
            }
}

__global__ __launch_bounds__(256) void gemm_out(const u16* __restrict__ ctx,
                                                const u16* __restrict__ wo,
                                                float* __restrict__ out) {
    __shared__ u16 As[128 * 64];
    __shared__ u16 Bs[128 * 64];
    const int m0 = blockIdx.x * 128, n0 = blockIdx.y * 128;
    f32x4 acc[4][4];
    gemm_128_mainloop(ctx, wo, As, Bs, m0, n0, acc);

    const int lane = threadIdx.x & 63, wid = threadIdx.x >> 6;
    const int wr = (wid >> 1) * 64, wc = (wid & 1) * 64;
    const int l15 = lane & 15, l4 = lane >> 4;
#pragma unroll
    for (int mi = 0; mi < 4; mi++)
#pragma unroll
        for (int ni = 0; ni < 4; ni++)
#pragma unroll
            for (int j = 0; j < 4; j++) {
                int m = m0 + wr + mi * 16 + l4 * 4 + j;
                int n = n0 + wc + ni * 16 + l15;
                out[m * DD + n] = acc[mi][ni][j];
            }
}

// ---------------------------------------------------------------- flash attention v15 (r17, passed, 88.4us)
// FROZEN: six interventions (occupancy x2, setprio, dovetail, grid-balance,
// V-hoist) all null/negative -> this structure's floor. v10 math + hoisted V
// fragments, single store->read fence, 4-ring K/V, counted vmcnt, (512,2).

__device__ __forceinline__ void stage_kv(const u16* __restrict__ Kb, const u16* __restrict__ Vb,
                                         u16* Kd, u16* Vd, int kt, int tid, int wid) {
    int r = tid >> 3, cc = tid & 7;
    int cs = cc ^ (r & 7);  // pre-swizzled global source, linear LDS dest
    gll16(Kb + (kt * 64 + r) * DKK + cs * 8, Kd + wid * 64 * 8);
    gll16(Vb + r * TT + kt * 64 + cs * 8, Vd + wid * 64 * 8);
}

__device__ __forceinline__ void load_qfrag16(const u16* Qb, int qbase, int l15, int l4,
                                             bf16x8 qf[2]) {
#pragma unroll
    for (int kc = 0; kc < 2; kc++) {
        const u16* p = Qb + (qbase + l15) * DKK + kc * 32 + l4 * 8;
        union { uint4 u; u16 h[8]; } cv;
        cv.u = *reinterpret_cast<const uint4*>(p);
        u16 o[8];
#pragma unroll
        for (int e = 0; e < 8; e++) o[e] = f2bf(bf2f(cv.h[e]) * QSCL);
        __builtin_memcpy(&qf[kc], o, 16);
    }
}

__device__ __forceinline__ void write_ctx16(u16* __restrict__ ctx, int b, int h, int qbase,
                                            int l15, int l4, const f32x4 acc[4],
                                            const f32x4 lacc) {
#pragma unroll
    for (int j = 0; j < 4; j++) {
        float inv = 1.0f / lacc[j];
        int t = qbase + l4 * 4 + j;
#pragma unroll
        for (int cf = 0; cf < 4; cf++) {
            int dk = cf * 16 + l15;
            ctx[((size_t)(b * TT + t)) * DD + h * 64 + dk] = f2bf(acc[cf][j] * inv);
        }
    }
}

// One full QK -> (V-hoist) -> exp -> P-LDS -> PV step for one side (16 q-rows).
__device__ __forceinline__ void attn_side(const bf16x8 qf[2], f32x4 acc[4], f32x4& lacc,
                                          const char* Kl, const char* Vl, char* Pw,
                                          bf16x8 onef, int l15, int l4,
                                          bool domask, int kt, int qbase) {
    const f32x4 z4 = {0.f, 0.f, 0.f, 0.f};
    f32x4 s[4];
#pragma unroll
    for (int cf = 0; cf < 4; cf++) s[cf] = z4;

    // ---- S = Q.K^T (A = Q, B = K)
#pragma unroll
    for (int kc = 0; kc < 2; kc++) {
#pragma unroll
        for (int cf = 0; cf < 4; cf++) {
            int kr = cf * 16 + l15;
            int cw = (l4 + kc * 4) ^ (kr & 7);
            bf16x8 kf = *reinterpret_cast<const bf16x8*>(Kl + kr * 128 + cw * 16);
            s[cf] = __builtin_amdgcn_mfma_f32_16x16x32_bf16(qf[kc], kf, s[cf], 0, 0, 0);
        }
    }

    // ---- HOISTED V-fragment loads: latency hides under the exp block.
    bf16x8 vf[2][4];
#pragma unroll
    for (int kc = 0; kc < 2; kc++)
#pragma unroll
        for (int cf = 0; cf < 4; cf++) {
            int vr = cf * 16 + l15;
            int vw = (l4 + kc * 4) ^ (vr & 7);
            vf[kc][cf] = *reinterpret_cast<const bf16x8*>(Vl + vr * 128 + vw * 16);
        }

    // ---- mask + exp (no max subtraction) + P -> per-wave LDS (scalar f2bf)
#pragma unroll
    for (int cf = 0; cf < 4; cf++)
#pragma unroll
        for (int j = 0; j < 4; j++) {
            float v = s[cf][j];
            if (domask) {
                int kk = kt * 64 + cf * 16 + l15;       // key (col = l15)
                int qq = qbase + l4 * 4 + j;            // query (row = l4*4+j)
                if (kk > qq) v = -__builtin_huge_valf();
            }
            float p = EXPW(v);
            int r = l4 * 4 + j;
            int col = cf * 16 + l15;
            int byte = r * 128 + (((col >> 3) ^ (r & 7)) << 4) + (col & 7) * 2;
            *reinterpret_cast<u16*>(Pw + byte) = f2bf(p);
        }

    // ordering fence: commit P stores before PV fragment loads (r6/r7 lesson)
    asm volatile("s_waitcnt lgkmcnt(0)" ::: "memory");
    __builtin_amdgcn_sched_barrier(0);

    // ---- PV (+ ones-MFMA row-sum); P read back as A-frag, V already in regs
#pragma unroll
    for (int kc = 0; kc < 2; kc++) {
        int cwp = (l4 + kc * 4) ^ (l15 & 7);
        bf16x8 pa = *reinterpret_cast<const bf16x8*>(Pw + l15 * 128 + cwp * 16);
#pragma unroll
        for (int cf = 0; cf < 4; cf++)
            acc[cf] = __builtin_amdgcn_mfma_f32_16x16x32_bf16(pa, vf[kc][cf], acc[cf], 0, 0, 0);
        lacc = __builtin_amdgcn_mfma_f32_16x16x32_bf16(pa, onef, lacc, 0, 0, 0);
    }
}

// grid (64, 8): x = bh (XCD-clustering), y = jA. Wave owns 16 rows of jA and 16 of 15-jA.
__global__ __launch_bounds__(512, 2) void attn_fwd(const u16* __restrict__ Qg,
                                                   const u16* __restrict__ Kg,
                                                   const u16* __restrict__ Vtg,
                                                   u16* __restrict__ ctx) {
    __shared__ u16 Kld[4][64 * 64];   // 32 KB (4-deep ring)
    __shared__ u16 Vld[4][64 * 64];   // 32 KB
    __shared__ u16 Pld[8][16 * 64];   // 16 KB (one per-wave buffer, sides reuse)

    const int tid = threadIdx.x;
    const int lane = tid & 63, wid = tid >> 6;
    const int l15 = lane & 15, l4 = lane >> 4;
    const int bh = blockIdx.x;
    const int jA = blockIdx.y, jB = 15 - jA;
    const int qbaseA = jA * 128 + wid * 16;
    const int qbaseB = jB * 128 + wid * 16;
    const int nA = 2 * jA + 1 + (wid >> 2);  // causal k-tile count for this wave's 16 rows
    const int nB = 2 * jB + 1 + (wid >> 2);
    const int nkt = 2 * jB + 2;              // block trip count (>= 18)

    const u16* Qb = Qg + (size_t)bh * TT * DKK;
    const u16* Kb = Kg + (size_t)bh * TT * DKK;
    const u16* Vb = Vtg + (size_t)bh * DKK * TT;

    bf16x8 qfA[2], qfB[2];
    load_qfrag16(Qb, qbaseA, l15, l4, qfA);
    load_qfrag16(Qb, qbaseB, l15, l4, qfB);

    // ones B-fragment for the row-sum MFMA
    bf16x8 onef;
    {
        union { bf16x8 v; u16 h[8]; } o;
#pragma unroll
        for (int e = 0; e < 8; e++) o.h[e] = 0x3F80;  // bf16 1.0
        onef = o.v;
    }

    f32x4 accA[4], accB[4], laccA, laccB;
    const f32x4 z4 = {0.f, 0.f, 0.f, 0.f};
#pragma unroll
    for (int j = 0; j < 4; j++) { accA[j] = z4; accB[j] = z4; }
    laccA = z4; laccB = z4;

    char* Pw = reinterpret_cast<char*>(&Pld[wid][0]);

    // prologue: 2 tiles in flight
    stage_kv(Kb, Vb, Kld[0], Vld[0], 0, tid, wid);
    stage_kv(Kb, Vb, Kld[1], Vld[1], 1, tid, wid);

    for (int kt = 0; kt < nkt; kt++) {
        if (kt + 2 < nkt) {
            stage_kv(Kb, Vb, Kld[(kt + 2) & 3], Vld[(kt + 2) & 3], kt + 2, tid, wid);
            asm volatile("s_waitcnt vmcnt(4)" ::: "memory");  // tiles kt+1,kt+2 in flight
        } else if (kt + 1 < nkt) {
            asm volatile("s_waitcnt vmcnt(2)" ::: "memory");  // tile kt+1 in flight
        } else {
            asm volatile("s_waitcnt vmcnt(0)" ::: "memory");
        }
        __syncthreads();  // single barrier per tile

        const char* Kl = reinterpret_cast<const char*>(Kld[kt & 3]);
        const char* Vl = reinterpret_cast<const char*>(Vld[kt & 3]);

        if (kt < nA)
            attn_side(qfA, accA, laccA, Kl, Vl, Pw, onef, l15, l4, kt == nA - 1, kt, qbaseA);
        if (kt < nB)
            attn_side(qfB, accB, laccB, Kl, Vl, Pw, onef, l15, l4, kt == nB - 1, kt, qbaseB);
    }

    const int b = bh >> 4, h = bh & 15;
    write_ctx16(ctx, b, h, qbaseA, l15, l4, accA, laccA);
    write_ctx16(ctx, b, h, qbaseB, l15, l4, accB, laccB);
}

// ---------------------------------------------------------------- launch
extern "C" void kernel_launch(void* const* d_in, const int* in_sizes, int n_in,
                              void* d_out, int out_size, void* d_ws, size_t ws_size,
                              hipStream_t stream) {
    const float* x = (const float*)d_in[0];
    const float* Wq = (const float*)d_in[1];
    const float* Wk = (const float*)d_in[2];
    const float* Wv = (const float*)d_in[3];
    const float* Wo = (const float*)d_in[4];

    const int nX = BB * TT * DD;        // 8388608
    const int nW = DD * DD;             // 1048576
    const int nQ = BB * HH * TT * DKK;  // 8388608

    u16* xb = (u16*)d_ws;
    u16* wqb = xb + nX;     // wq|wk|wv|wo contiguous
    u16* wkb = wqb + nW;
    u16* wvb = wkb + nW;
    u16* wob = wvb + nW;
    u16* Qb = wob + nW;
    u16* Kb = Qb + nQ;
    u16* Vtb = Kb + nQ;
    u16* ctxb = Vtb + nQ;

    cast_all<<<dim3(1024, 5), 256, 0, stream>>>(x, Wq, Wk, Wv, Wo, xb, wqb, nX, nW);

    gemm_qkv<<<dim3((BB * TT) / 128, DD / 128, 3), 256, 0, stream>>>(xb, wqb, wkb, wvb, Qb, Kb, Vtb);

    attn_fwd<<<dim3(64, 8), 512, 0, stream>>>(Qb, Kb, Vtb, ctxb);

    gemm_out<<<dim3((BB * TT) / 128, DD / 128), 256, 0, stream>>>(ctxb, wob, (float*)d_out);
}

// Round 19
// 196.347 us; speedup vs baseline: 1.0819x; 1.0819x over previous
//
#include <hip/hip_runtime.h>
#include <hip/hip_bf16.h>
#include <stdint.h>

#define BB 4
#define TT 2048
#define DD 1024
#define HH 16
#define DKK 64

typedef unsigned short u16;
typedef unsigned int u32;
typedef __bf16 bf16_t;
typedef bf16_t bf16x8 __attribute__((ext_vector_type(8)));
typedef float f32x4 __attribute__((ext_vector_type(4)));

#if __has_builtin(__builtin_amdgcn_exp2f)
#define EXPW(x) __builtin_amdgcn_exp2f(x)
#define QSCL 0.1803368801111244f  /* 0.125 * log2(e): exp done in base-2 domain */
#else
#define EXPW(x) __expf(x)
#define QSCL 0.125f
#endif

__device__ __forceinline__ float bf2f(u16 u) {
    u32 x = ((u32)u) << 16;
    float f;
    __builtin_memcpy(&f, &x, 4);
    return f;
}
__device__ __forceinline__ u16 f2bf(float f) {
    u32 x;
    __builtin_memcpy(&x, &f, 4);
    x += 0x7fffu + ((x >> 16) & 1u);  // RNE truncate (no NaN inputs here)
    return (u16)(x >> 16);
}
// NOTE: v_cvt_pk_bf16_f32 inline asm is BANNED: every NaN failure this session
// (r6, r7, r16) contained it; every kernel without it passed.

// async global->LDS, 16B per lane; l must be the WAVE-UNIFORM base (lane*16 added by HW)
__device__ __forceinline__ void gll16(const u16* g, u16* l) {
    __builtin_amdgcn_global_load_lds((const __attribute__((address_space(1))) u32*)g,
                                     (__attribute__((address_space(3))) u32*)l, 16, 0, 0);
}

// ---------------------------------------------------------------- casts (merged: 1 dispatch)
__global__ void cast_all(const float* __restrict__ x,
                         const float* __restrict__ w0, const float* __restrict__ w1,
                         const float* __restrict__ w2, const float* __restrict__ w3,
                         u16* __restrict__ outx, u16* __restrict__ outw, int nX, int nW) {
    const float* src;
    u16* dst;
    int n;
    if (blockIdx.y == 0) { src = x; dst = outx; n = nX; }
    else {
        src = (blockIdx.y == 1) ? w0 : (blockIdx.y == 2) ? w1 : (blockIdx.y == 3) ? w2 : w3;
        dst = outw + (size_t)(blockIdx.y - 1) * nW;
        n = nW;
    }
    int i = (blockIdx.x * blockDim.x + threadIdx.x) * 4;
    int stride = gridDim.x * blockDim.x * 4;
    for (; i < n; i += stride) {
        float4 v = *reinterpret_cast<const float4*>(src + i);
        uint2 pk;
        pk.x = (u32)f2bf(v.x) | ((u32)f2bf(v.y) << 16);
        pk.y = (u32)f2bf(v.z) | ((u32)f2bf(v.w) << 16);
        *reinterpret_cast<uint2*>(dst + i) = pk;
    }
}

// ---------------------------------------------------------------- GEMM core
// r11-EXACT m97-style loop: BK=32, 2 barriers, vmcnt(0), 16 KB LDS, 4 blocks/CU.
// Structure experiments all REFUTED: r12 ring-3/single-barrier (73->96us,
// occupancy loss), r18 BK=64 (73->101us, 128B row stride -> 3x bank conflicts).
// This is the measured optimum for the 128^2 tile family (guide m99/m100/m132).
__device__ __forceinline__ void gemm_128_mainloop(const u16* __restrict__ A,
                                                  const u16* __restrict__ W,
                                                  u16* As, u16* Bs,
                                                  int m0, int n0, f32x4 acc[4][4]) {
    const int tid = threadIdx.x;
    const int lane = tid & 63;
    const int wid = tid >> 6;
    const int wr = (wid >> 1) * 64, wc = (wid & 1) * 64;
    const int l15 = lane & 15, l4 = lane >> 4;

    const f32x4 z4 = {0.f, 0.f, 0.f, 0.f};
#pragma unroll
    for (int i = 0; i < 4; i++)
#pragma unroll
        for (int j = 0; j < 4; j++) acc[i][j] = z4;

    const int r0 = tid >> 2;
    const int c0 = (tid & 3) * 8;

    for (int k0 = 0; k0 < DD; k0 += 32) {
        __syncthreads();
        gll16(A + (m0 + r0) * DD + k0 + c0, As + (wid * 64) * 8);
        gll16(A + (m0 + 64 + r0) * DD + k0 + c0, As + (256 + wid * 64) * 8);
        gll16(W + (n0 + r0) * DD + k0 + c0, Bs + (wid * 64) * 8);
        gll16(W + (n0 + 64 + r0) * DD + k0 + c0, Bs + (256 + wid * 64) * 8);
        asm volatile("s_waitcnt vmcnt(0)" ::: "memory");
        __syncthreads();

        bf16x8 af[4], bfr[4];
#pragma unroll
        for (int mi = 0; mi < 4; mi++)
            af[mi] = *reinterpret_cast<const bf16x8*>(As + (wr + mi * 16 + l15) * 32 + l4 * 8);
#pragma unroll
        for (int ni = 0; ni < 4; ni++)
            bfr[ni] = *reinterpret_cast<const bf16x8*>(Bs + (wc + ni * 16 + l15) * 32 + l4 * 8);
#pragma unroll
        for (int mi = 0; mi < 4; mi++)
#pragma unroll
            for (int ni = 0; ni < 4; ni++)
                acc[mi][ni] =
                    __builtin_amdgcn_mfma_f32_16x16x32_bf16(af[mi], bfr[ni], acc[mi][ni], 0, 0, 0);
    }
}

// z=0: Q  -> [b][h][t][dk] bf16 ; z=1: K same ; z=2: V -> [b][h][dk][t] bf16 (transposed)
__global__ __launch_bounds__(256) void gemm_qkv(const u16* __restrict__ xb,
                                                const u16* __restrict__ wq,
                                                const u16* __restrict__ wk,
                                                const u16* __restrict__ wv,
                                                u16* __restrict__ Qo, u16* __restrict__ Ko,
                                                u16* __restrict__ Vto) {
    __shared__ u16 As[128 * 32];
    __shared__ u16 Bs[128 * 32];
    const int z = blockIdx.z;
    const u16* W = (z == 0) ? wq : (z == 1) ? wk : wv;
    u16* dst = (z == 0) ? Qo : (z == 1) ? Ko : Vto;
    const int m0 = blockIdx.x * 128, n0 = blockIdx.y * 128;

    f32x4 acc[4][4];
    gemm_128_mainloop(xb, W, As, Bs, m0, n0, acc);

    const int lane = threadIdx.x & 63, wid = threadIdx.x >> 6;
    const int wr = (wid >> 1) * 64, wc = (wid & 1) * 64;
    const int l15 = lane & 15, l4 = lane >> 4;
#pragma unroll
    for (int mi = 0; mi < 4; mi++)
#pragma unroll
        for (int ni = 0; ni < 4; ni++)
#pragma unroll
            for (int j = 0; j < 4; j++) {
                int m = m0 + wr + mi * 16 + l4 * 4 + j;  // token
                int n = n0 + wc + ni * 16 + l15;          // feature e = h*64+dk
                int b = m >> 11, t = m & (TT - 1);
                int h = n >> 6, dk = n & 63;
                u16 v = f2bf(acc[mi][ni][j]);
                if (z < 2)
                    dst[((b * HH + h) * TT + t) * DKK + dk] = v;
                else
                    dst[((b * HH + h) * DKK + dk) * TT + t] = v;
            }
}

__global__ __launch_bounds__(256) void gemm_out(const u16* __restrict__ ctx,
                                                const u16* __restrict__ wo,
                                                float* __restrict__ out) {
    __shared__ u16 As[128 * 32];
    __shared__ u16 Bs[128 * 32];
    const int m0 = blockIdx.x * 128, n0 = blockIdx.y * 128;
    f32x4 acc[4][4];
    gemm_128_mainloop(ctx, wo, As, Bs, m0, n0, acc);

    const int lane = threadIdx.x & 63, wid = threadIdx.x >> 6;
    const int wr = (wid >> 1) * 64, wc = (wid & 1) * 64;
    const int l15 = lane & 15, l4 = lane >> 4;
#pragma unroll
    for (int mi = 0; mi < 4; mi++)
#pragma unroll
        for (int ni = 0; ni < 4; ni++)
#pragma unroll
            for (int j = 0; j < 4; j++) {
                int m = m0 + wr + mi * 16 + l4 * 4 + j;
                int n = n0 + wc + ni * 16 + l15;
                out[m * DD + n] = acc[mi][ni][j];
            }
}

// ---------------------------------------------------------------- flash attention v15 (r17, passed, 88.4us)
// FROZEN at the measured structural floor: six interventions (occupancy x2,
// setprio, dovetail, grid-balance, V-hoist, cvt_pk) all null/negative. v10 math
// + hoisted V fragments, single store->read fence, 4-ring K/V, counted vmcnt,
// (512,2) = proven VGPR regime, grid (64,8) = XCD-local K/V (FETCH 36MB).

__device__ __forceinline__ void stage_kv(const u16* __restrict__ Kb, const u16* __restrict__ Vb,
                                         u16* Kd, u16* Vd, int kt, int tid, int wid) {
    int r = tid >> 3, cc = tid & 7;
    int cs = cc ^ (r & 7);  // pre-swizzled global source, linear LDS dest
    gll16(Kb + (kt * 64 + r) * DKK + cs * 8, Kd + wid * 64 * 8);
    gll16(Vb + r * TT + kt * 64 + cs * 8, Vd + wid * 64 * 8);
}

__device__ __forceinline__ void load_qfrag16(const u16* Qb, int qbase, int l15, int l4,
                                             bf16x8 qf[2]) {
#pragma unroll
    for (int kc = 0; kc < 2; kc++) {
        const u16* p = Qb + (qbase + l15) * DKK + kc * 32 + l4 * 8;
        union { uint4 u; u16 h[8]; } cv;
        cv.u = *reinterpret_cast<const uint4*>(p);
        u16 o[8];
#pragma unroll
        for (int e = 0; e < 8; e++) o[e] = f2bf(bf2f(cv.h[e]) * QSCL);
        __builtin_memcpy(&qf[kc], o, 16);
    }
}

__device__ __forceinline__ void write_ctx16(u16* __restrict__ ctx, int b, int h, int qbase,
                                            int l15, int l4, const f32x4 acc[4],
                                            const f32x4 lacc) {
#pragma unroll
    for (int j = 0; j < 4; j++) {
        float inv = 1.0f / lacc[j];
        int t = qbase + l4 * 4 + j;
#pragma unroll
        for (int cf = 0; cf < 4; cf++) {
            int dk = cf * 16 + l15;
            ctx[((size_t)(b * TT + t)) * DD + h * 64 + dk] = f2bf(acc[cf][j] * inv);
        }
    }
}

// One full QK -> (V-hoist) -> exp -> P-LDS -> PV step for one side (16 q-rows).
__device__ __forceinline__ void attn_side(const bf16x8 qf[2], f32x4 acc[4], f32x4& lacc,
                                          const char* Kl, const char* Vl, char* Pw,
                                          bf16x8 onef, int l15, int l4,
                                          bool domask, int kt, int qbase) {
    const f32x4 z4 = {0.f, 0.f, 0.f, 0.f};
    f32x4 s[4];
#pragma unroll
    for (int cf = 0; cf < 4; cf++) s[cf] = z4;

    // ---- S = Q.K^T (A = Q, B = K)
#pragma unroll
    for (int kc = 0; kc < 2; kc++) {
#pragma unroll
        for (int cf = 0; cf < 4; cf++) {
            int kr = cf * 16 + l15;
            int cw = (l4 + kc * 4) ^ (kr & 7);
            bf16x8 kf = *reinterpret_cast<const bf16x8*>(Kl + kr * 128 + cw * 16);
            s[cf] = __builtin_amdgcn_mfma_f32_16x16x32_bf16(qf[kc], kf, s[cf], 0, 0, 0);
        }
    }

    // ---- HOISTED V-fragment loads: latency hides under the exp block.
    bf16x8 vf[2][4];
#pragma unroll
    for (int kc = 0; kc < 2; kc++)
#pragma unroll
        for (int cf = 0; cf < 4; cf++) {
            int vr = cf * 16 + l15;
            int vw = (l4 + kc * 4) ^ (vr & 7);
            vf[kc][cf] = *reinterpret_cast<const bf16x8*>(Vl + vr * 128 + vw * 16);
        }

    // ---- mask + exp (no max subtraction) + P -> per-wave LDS (scalar f2bf)
#pragma unroll
    for (int cf = 0; cf < 4; cf++)
#pragma unroll
        for (int j = 0; j < 4; j++) {
            float v = s[cf][j];
            if (domask) {
                int kk = kt * 64 + cf * 16 + l15;       // key (col = l15)
                int qq = qbase + l4 * 4 + j;            // query (row = l4*4+j)
                if (kk > qq) v = -__builtin_huge_valf();
            }
            float p = EXPW(v);
            int r = l4 * 4 + j;
            int col = cf * 16 + l15;
            int byte = r * 128 + (((col >> 3) ^ (r & 7)) << 4) + (col & 7) * 2;
            *reinterpret_cast<u16*>(Pw + byte) = f2bf(p);
        }

    // ordering fence: commit P stores before PV fragment loads (r6/r7 lesson)
    asm volatile("s_waitcnt lgkmcnt(0)" ::: "memory");
    __builtin_amdgcn_sched_barrier(0);

    // ---- PV (+ ones-MFMA row-sum); P read back as A-frag, V already in regs
#pragma unroll
    for (int kc = 0; kc < 2; kc++) {
        int cwp = (l4 + kc * 4) ^ (l15 & 7);
        bf16x8 pa = *reinterpret_cast<const bf16x8*>(Pw + l15 * 128 + cwp * 16);
#pragma unroll
        for (int cf = 0; cf < 4; cf++)
            acc[cf] = __builtin_amdgcn_mfma_f32_16x16x32_bf16(pa, vf[kc][cf], acc[cf], 0, 0, 0);
        lacc = __builtin_amdgcn_mfma_f32_16x16x32_bf16(pa, onef, lacc, 0, 0, 0);
    }
}

// grid (64, 8): x = bh (XCD-clustering), y = jA. Wave owns 16 rows of jA and 16 of 15-jA.
__global__ __launch_bounds__(512, 2) void attn_fwd(const u16* __restrict__ Qg,
                                                   const u16* __restrict__ Kg,
                                                   const u16* __restrict__ Vtg,
                                                   u16* __restrict__ ctx) {
    __shared__ u16 Kld[4][64 * 64];   // 32 KB (4-deep ring)
    __shared__ u16 Vld[4][64 * 64];   // 32 KB
    __shared__ u16 Pld[8][16 * 64];   // 16 KB (one per-wave buffer, sides reuse)

    const int tid = threadIdx.x;
    const int lane = tid & 63, wid = tid >> 6;
    const int l15 = lane & 15, l4 = lane >> 4;
    const int bh = blockIdx.x;
    const int jA = blockIdx.y, jB = 15 - jA;
    const int qbaseA = jA * 128 + wid * 16;
    const int qbaseB = jB * 128 + wid * 16;
    const int nA = 2 * jA + 1 + (wid >> 2);  // causal k-tile count for this wave's 16 rows
    const int nB = 2 * jB + 1 + (wid >> 2);
    const int nkt = 2 * jB + 2;              // block trip count (>= 18)

    const u16* Qb = Qg + (size_t)bh * TT * DKK;
    const u16* Kb = Kg + (size_t)bh * TT * DKK;
    const u16* Vb = Vtg + (size_t)bh * DKK * TT;

    bf16x8 qfA[2], qfB[2];
    load_qfrag16(Qb, qbaseA, l15, l4, qfA);
    load_qfrag16(Qb, qbaseB, l15, l4, qfB);

    // ones B-fragment for the row-sum MFMA
    bf16x8 onef;
    {
        union { bf16x8 v; u16 h[8]; } o;
#pragma unroll
        for (int e = 0; e < 8; e++) o.h[e] = 0x3F80;  // bf16 1.0
        onef = o.v;
    }

    f32x4 accA[4], accB[4], laccA, laccB;
    const f32x4 z4 = {0.f, 0.f, 0.f, 0.f};
#pragma unroll
    for (int j = 0; j < 4; j++) { accA[j] = z4; accB[j] = z4; }
    laccA = z4; laccB = z4;

    char* Pw = reinterpret_cast<char*>(&Pld[wid][0]);

    // prologue: 2 tiles in flight
    stage_kv(Kb, Vb, Kld[0], Vld[0], 0, tid, wid);
    stage_kv(Kb, Vb, Kld[1], Vld[1], 1, tid, wid);

    for (int kt = 0; kt < nkt; kt++) {
        if (kt + 2 < nkt) {
            stage_kv(Kb, Vb, Kld[(kt + 2) & 3], Vld[(kt + 2) & 3], kt + 2, tid, wid);
            asm volatile("s_waitcnt vmcnt(4)" ::: "memory");  // tiles kt+1,kt+2 in flight
        } else if (kt + 1 < nkt) {
            asm volatile("s_waitcnt vmcnt(2)" ::: "memory");  // tile kt+1 in flight
        } else {
            asm volatile("s_waitcnt vmcnt(0)" ::: "memory");
        }
        __syncthreads();  // single barrier per tile

        const char* Kl = reinterpret_cast<const char*>(Kld[kt & 3]);
        const char* Vl = reinterpret_cast<const char*>(Vld[kt & 3]);

        if (kt < nA)
            attn_side(qfA, accA, laccA, Kl, Vl, Pw, onef, l15, l4, kt == nA - 1, kt, qbaseA);
        if (kt < nB)
            attn_side(qfB, accB, laccB, Kl, Vl, Pw, onef, l15, l4, kt == nB - 1, kt, qbaseB);
    }

    const int b = bh >> 4, h = bh & 15;
    write_ctx16(ctx, b, h, qbaseA, l15, l4, accA, laccA);
    write_ctx16(ctx, b, h, qbaseB, l15, l4, accB, laccB);
}

// ---------------------------------------------------------------- launch
extern "C" void kernel_launch(void* const* d_in, const int* in_sizes, int n_in,
                              void* d_out, int out_size, void* d_ws, size_t ws_size,
                              hipStream_t stream) {
    const float* x = (const float*)d_in[0];
    const float* Wq = (const float*)d_in[1];
    const float* Wk = (const float*)d_in[2];
    const float* Wv = (const float*)d_in[3];
    const float* Wo = (const float*)d_in[4];

    const int nX = BB * TT * DD;        // 8388608
    const int nW = DD * DD;             // 1048576
    const int nQ = BB * HH * TT * DKK;  // 8388608

    u16* xb = (u16*)d_ws;
    u16* wqb = xb + nX;     // wq|wk|wv|wo contiguous
    u16* wkb = wqb + nW;
    u16* wvb = wkb + nW;
    u16* wob = wvb + nW;
    u16* Qb = wob + nW;
    u16* Kb = Qb + nQ;
    u16* Vtb = Kb + nQ;
    u16* ctxb = Vtb + nQ;

    cast_all<<<dim3(1024, 5), 256, 0, stream>>>(x, Wq, Wk, Wv, Wo, xb, wqb, nX, nW);

    gemm_qkv<<<dim3((BB * TT) / 128, DD / 128, 3), 256, 0, stream>>>(xb, wqb, wkb, wvb, Qb, Kb, Vtb);

    attn_fwd<<<dim3(64, 8), 512, 0, stream>>>(Qb, Kb, Vtb, ctxb);

    gemm_out<<<dim3((BB * TT) / 128, DD / 128), 256, 0, stream>>>(ctxb, wob, (float*)d_out);
}

// Round 20
// 191.274 us; speedup vs baseline: 1.1106x; 1.0265x over previous
//
#include <hip/hip_runtime.h>
#include <hip/hip_bf16.h>
#include <stdint.h>

#define BB 4
#define TT 2048
#define DD 1024
#define HH 16
#define DKK 64

typedef unsigned short u16;
typedef unsigned int u32;
typedef __bf16 bf16_t;
typedef bf16_t bf16x8 __attribute__((ext_vector_type(8)));
typedef float f32x4 __attribute__((ext_vector_type(4)));

#if __has_builtin(__builtin_amdgcn_exp2f)
#define EXPW(x) __builtin_amdgcn_exp2f(x)
#define QSCL 0.1803368801111244f  /* 0.125 * log2(e): exp done in base-2 domain */
#else
#define EXPW(x) __expf(x)
#define QSCL 0.125f
#endif

__device__ __forceinline__ float bf2f(u16 u) {
    u32 x = ((u32)u) << 16;
    float f;
    __builtin_memcpy(&f, &x, 4);
    return f;
}
__device__ __forceinline__ u16 f2bf(float f) {
    u32 x;
    __builtin_memcpy(&x, &f, 4);
    x += 0x7fffu + ((x >> 16) & 1u);  // RNE truncate (no NaN inputs here)
    return (u16)(x >> 16);
}
// NOTE: v_cvt_pk_bf16_f32 inline asm is BANNED: every NaN failure this session
// (r6, r7, r16) contained it; every kernel without it passed.

// async global->LDS, 16B per lane; l must be the WAVE-UNIFORM base (lane*16 added by HW)
__device__ __forceinline__ void gll16(const u16* g, u16* l) {
    __builtin_amdgcn_global_load_lds((const __attribute__((address_space(1))) u32*)g,
                                     (__attribute__((address_space(3))) u32*)l, 16, 0, 0);
}

// ---------------------------------------------------------------- casts (merged: 1 dispatch)
__global__ void cast_all(const float* __restrict__ x,
                         const float* __restrict__ w0, const float* __restrict__ w1,
                         const float* __restrict__ w2, const float* __restrict__ w3,
                         u16* __restrict__ outx, u16* __restrict__ outw, int nX, int nW) {
    const float* src;
    u16* dst;
    int n;
    if (blockIdx.y == 0) { src = x; dst = outx; n = nX; }
    else {
        src = (blockIdx.y == 1) ? w0 : (blockIdx.y == 2) ? w1 : (blockIdx.y == 3) ? w2 : w3;
        dst = outw + (size_t)(blockIdx.y - 1) * nW;
        n = nW;
    }
    int i = (blockIdx.x * blockDim.x + threadIdx.x) * 4;
    int stride = gridDim.x * blockDim.x * 4;
    for (; i < n; i += stride) {
        float4 v = *reinterpret_cast<const float4*>(src + i);
        uint2 pk;
        pk.x = (u32)f2bf(v.x) | ((u32)f2bf(v.y) << 16);
        pk.y = (u32)f2bf(v.z) | ((u32)f2bf(v.w) << 16);
        *reinterpret_cast<uint2*>(dst + i) = pk;
    }
}

// ---------------------------------------------------------------- GEMM core, BK=64 + swizzle
// C[m][n] = sum_k A[m][k]*W[n][k] (TN), 128x128 tile, K-slab 64, 2-barrier schedule.
// r18's BK=64 regressed SOLELY via bank conflicts (6.3M->18.9M = ~20us at 2.4GHz;
// 128B row stride). Fix: the ATTN-PROVEN swizzle pair (measured 0.0 conflicts all
// session on identical 128B-row geometry): stage with pre-swizzled global source
// cs = cc^(r&7) (linear LDS dest, legal for global_load_lds), read fragments at
// physical chunk (kc*4+l4)^(row&7). Round-trip: LDS(r,cc) holds global chunk
// cc^(r&7); want chunk kc*4+l4 -> read cc = (kc*4+l4)^(r&7). Residual aliasing
// 2-way = free (m136). 16 K-steps (was 32) -> half the barrier/drain events.
__device__ __forceinline__ void gemm_128_mainloop(const u16* __restrict__ A,
                                                  const u16* __restrict__ W,
                                                  u16* As, u16* Bs,  // [128*64] each
                                                  int m0, int n0, f32x4 acc[4][4]) {
    const int tid = threadIdx.x;
    const int lane = tid & 63;
    const int wid = tid >> 6;
    const int wr = (wid >> 1) * 64, wc = (wid & 1) * 64;
    const int l15 = lane & 15, l4 = lane >> 4;

    const f32x4 z4 = {0.f, 0.f, 0.f, 0.f};
#pragma unroll
    for (int i = 0; i < 4; i++)
#pragma unroll
        for (int j = 0; j < 4; j++) acc[i][j] = z4;

    for (int k0 = 0; k0 < DD; k0 += 64) {
        __syncthreads();
        // stage A[128][64] + W[128][64]: 1024 chunks each, 4 issues/thread each.
        // id = iss*256 + tid -> LDS addr id*16B (base (iss*256+wid*64)*8 u16 is
        // wave-uniform, HW adds lane*16). r = id>>3, physical chunk cc = id&7,
        // global source chunk cs = cc ^ (r&7).
#pragma unroll
        for (int iss = 0; iss < 4; iss++) {
            int id = iss * 256 + tid;
            int r = id >> 3, cc = id & 7;
            int cs = cc ^ (r & 7);
            gll16(A + (m0 + r) * DD + k0 + cs * 8, As + (iss * 256 + wid * 64) * 8);
            gll16(W + (n0 + r) * DD + k0 + cs * 8, Bs + (iss * 256 + wid * 64) * 8);
        }
        asm volatile("s_waitcnt vmcnt(0)" ::: "memory");
        __syncthreads();

#pragma unroll
        for (int kc = 0; kc < 2; kc++) {
            bf16x8 af[4], bfr[4];
#pragma unroll
            for (int mi = 0; mi < 4; mi++) {
                int row = wr + mi * 16 + l15;
                int cw = (kc * 4 + l4) ^ (row & 7);
                af[mi] = *reinterpret_cast<const bf16x8*>(
                    reinterpret_cast<const char*>(As) + row * 128 + cw * 16);
            }
#pragma unroll
            for (int ni = 0; ni < 4; ni++) {
                int row = wc + ni * 16 + l15;
                int cw = (kc * 4 + l4) ^ (row & 7);
                bfr[ni] = *reinterpret_cast<const bf16x8*>(
                    reinterpret_cast<const char*>(Bs) + row * 128 + cw * 16);
            }
#pragma unroll
            for (int mi = 0; mi < 4; mi++)
#pragma unroll
                for (int ni = 0; ni < 4; ni++)
                    acc[mi][ni] = __builtin_amdgcn_mfma_f32_16x16x32_bf16(
                        af[mi], bfr[ni], acc[mi][ni], 0, 0, 0);
        }
    }
}

// z=0: Q  -> [b][h][t][dk] bf16 ; z=1: K same ; z=2: V -> [b][h][dk][t] bf16 (transposed)
__global__ __launch_bounds__(256) void gemm_qkv(const u16* __restrict__ xb,
                                                const u16* __restrict__ wq,
                                                const u16* __restrict__ wk,
                                                const u16* __restrict__ wv,
                                                u16* __restrict__ Qo, u16* __restrict__ Ko,
                                                u16* __restrict__ Vto) {
    __shared__ u16 As[128 * 64];   // 16 KB
    __shared__ u16 Bs[128 * 64];   // 16 KB
    const int z = blockIdx.z;
    const u16* W = (z == 0) ? wq : (z == 1) ? wk : wv;
    u16* dst = (z == 0) ? Qo : (z == 1) ? Ko : Vto;
    const int m0 = blockIdx.x * 128, n0 = blockIdx.y * 128;

    f32x4 acc[4][4];
    gemm_128_mainloop(xb, W, As, Bs, m0, n0, acc);

    const int lane = threadIdx.x & 63, wid = threadIdx.x >> 6;
    const int wr = (wid >> 1) * 64, wc = (wid & 1) * 64;
    const int l15 = lane & 15, l4 = lane >> 4;
#pragma unroll
    for (int mi = 0; mi < 4; mi++)
#pragma unroll
        for (int ni = 0; ni < 4; ni++)
#pragma unroll
            for (int j = 0; j < 4; j++) {
                int m = m0 + wr + mi * 16 + l4 * 4 + j;  // token
                int n = n0 + wc + ni * 16 + l15;          // feature e = h*64+dk
                int b = m >> 11, t = m & (TT - 1);
                int h = n >> 6, dk = n & 63;
                u16 v = f2bf(acc[mi][ni][j]);
                if (z < 2)
                    dst[((b * HH + h) * TT + t) * DKK + dk] = v;
                else
                    dst[((b * HH + h) * DKK + dk) * TT + t] = v;
            }
}

__global__ __launch_bounds__(256) void gemm_out(const u16* __restrict__ ctx,
                                                const u16* __restrict__ wo,
                                                float* __restrict__ out) {
    __shared__ u16 As[128 * 64];
    __shared__ u16 Bs[128 * 64];
    const int m0 = blockIdx.x * 128, n0 = blockIdx.y * 128;
    f32x4 acc[4][4];
    gemm_128_mainloop(ctx, wo, As, Bs, m0, n0, acc);

    const int lane = threadIdx.x & 63, wid = threadIdx.x >> 6;
    const int wr = (wid >> 1) * 64, wc = (wid & 1) * 64;
    const int l15 = lane & 15, l4 = lane >> 4;
#pragma unroll
    for (int mi = 0; mi < 4; mi++)
#pragma unroll
        for (int ni = 0; ni < 4; ni++)
#pragma unroll
            for (int j = 0; j < 4; j++) {
                int m = m0 + wr + mi * 16 + l4 * 4 + j;
                int n = n0 + wc + ni * 16 + l15;
                out[m * DD + n] = acc[mi][ni][j];
            }
}

// ---------------------------------------------------------------- flash attention v15 (r17/r19, 88.4us)
// FROZEN at the measured structural floor: six interventions all null/negative.

__device__ __forceinline__ void stage_kv(const u16* __restrict__ Kb, const u16* __restrict__ Vb,
                                         u16* Kd, u16* Vd, int kt, int tid, int wid) {
    int r = tid >> 3, cc = tid & 7;
    int cs = cc ^ (r & 7);  // pre-swizzled global source, linear LDS dest
    gll16(Kb + (kt * 64 + r) * DKK + cs * 8, Kd + wid * 64 * 8);
    gll16(Vb + r * TT + kt * 64 + cs * 8, Vd + wid * 64 * 8);
}

__device__ __forceinline__ void load_qfrag16(const u16* Qb, int qbase, int l15, int l4,
                                             bf16x8 qf[2]) {
#pragma unroll
    for (int kc = 0; kc < 2; kc++) {
        const u16* p = Qb + (qbase + l15) * DKK + kc * 32 + l4 * 8;
        union { uint4 u; u16 h[8]; } cv;
        cv.u = *reinterpret_cast<const uint4*>(p);
        u16 o[8];
#pragma unroll
        for (int e = 0; e < 8; e++) o[e] = f2bf(bf2f(cv.h[e]) * QSCL);
        __builtin_memcpy(&qf[kc], o, 16);
    }
}

__device__ __forceinline__ void write_ctx16(u16* __restrict__ ctx, int b, int h, int qbase,
                                            int l15, int l4, const f32x4 acc[4],
                                            const f32x4 lacc) {
#pragma unroll
    for (int j = 0; j < 4; j++) {
        float inv = 1.0f / lacc[j];
        int t = qbase + l4 * 4 + j;
#pragma unroll
        for (int cf = 0; cf < 4; cf++) {
            int dk = cf * 16 + l15;
            ctx[((size_t)(b * TT + t)) * DD + h * 64 + dk] = f2bf(acc[cf][j] * inv);
        }
    }
}

// One full QK -> (V-hoist) -> exp -> P-LDS -> PV step for one side (16 q-rows).
__device__ __forceinline__ void attn_side(const bf16x8 qf[2], f32x4 acc[4], f32x4& lacc,
                                          const char* Kl, const char* Vl, char* Pw,
                                          bf16x8 onef, int l15, int l4,
                                          bool domask, int kt, int qbase) {
    const f32x4 z4 = {0.f, 0.f, 0.f, 0.f};
    f32x4 s[4];
#pragma unroll
    for (int cf = 0; cf < 4; cf++) s[cf] = z4;

    // ---- S = Q.K^T (A = Q, B = K)
#pragma unroll
    for (int kc = 0; kc < 2; kc++) {
#pragma unroll
        for (int cf = 0; cf < 4; cf++) {
            int kr = cf * 16 + l15;
            int cw = (l4 + kc * 4) ^ (kr & 7);
            bf16x8 kf = *reinterpret_cast<const bf16x8*>(Kl + kr * 128 + cw * 16);
            s[cf] = __builtin_amdgcn_mfma_f32_16x16x32_bf16(qf[kc], kf, s[cf], 0, 0, 0);
        }
    }

    // ---- HOISTED V-fragment loads: latency hides under the exp block.
    bf16x8 vf[2][4];
#pragma unroll
    for (int kc = 0; kc < 2; kc++)
#pragma unroll
        for (int cf = 0; cf < 4; cf++) {
            int vr = cf * 16 + l15;
            int vw = (l4 + kc * 4) ^ (vr & 7);
            vf[kc][cf] = *reinterpret_cast<const bf16x8*>(Vl + vr * 128 + vw * 16);
        }

    // ---- mask + exp (no max subtraction) + P -> per-wave LDS (scalar f2bf)
#pragma unroll
    for (int cf = 0; cf < 4; cf++)
#pragma unroll
        for (int j = 0; j < 4; j++) {
            float v = s[cf][j];
            if (domask) {
                int kk = kt * 64 + cf * 16 + l15;       // key (col = l15)
                int qq = qbase + l4 * 4 + j;            // query (row = l4*4+j)
                if (kk > qq) v = -__builtin_huge_valf();
            }
            float p = EXPW(v);
            int r = l4 * 4 + j;
            int col = cf * 16 + l15;
            int byte = r * 128 + (((col >> 3) ^ (r & 7)) << 4) + (col & 7) * 2;
            *reinterpret_cast<u16*>(Pw + byte) = f2bf(p);
        }

    // ordering fence: commit P stores before PV fragment loads (r6/r7 lesson)
    asm volatile("s_waitcnt lgkmcnt(0)" ::: "memory");
    __builtin_amdgcn_sched_barrier(0);

    // ---- PV (+ ones-MFMA row-sum); P read back as A-frag, V already in regs
#pragma unroll
    for (int kc = 0; kc < 2; kc++) {
        int cwp = (l4 + kc * 4) ^ (l15 & 7);
        bf16x8 pa = *reinterpret_cast<const bf16x8*>(Pw + l15 * 128 + cwp * 16);
#pragma unroll
        for (int cf = 0; cf < 4; cf++)
            acc[cf] = __builtin_amdgcn_mfma_f32_16x16x32_bf16(pa, vf[kc][cf], acc[cf], 0, 0, 0);
        lacc = __builtin_amdgcn_mfma_f32_16x16x32_bf16(pa, onef, lacc, 0, 0, 0);
    }
}

// grid (64, 8): x = bh (XCD-clustering), y = jA. Wave owns 16 rows of jA and 16 of 15-jA.
__global__ __launch_bounds__(512, 2) void attn_fwd(const u16* __restrict__ Qg,
                                                   const u16* __restrict__ Kg,
                                                   const u16* __restrict__ Vtg,
                                                   u16* __restrict__ ctx) {
    __shared__ u16 Kld[4][64 * 64];   // 32 KB (4-deep ring)
    __shared__ u16 Vld[4][64 * 64];   // 32 KB
    __shared__ u16 Pld[8][16 * 64];   // 16 KB (one per-wave buffer, sides reuse)

    const int tid = threadIdx.x;
    const int lane = tid & 63, wid = tid >> 6;
    const int l15 = lane & 15, l4 = lane >> 4;
    const int bh = blockIdx.x;
    const int jA = blockIdx.y, jB = 15 - jA;
    const int qbaseA = jA * 128 + wid * 16;
    const int qbaseB = jB * 128 + wid * 16;
    const int nA = 2 * jA + 1 + (wid >> 2);  // causal k-tile count for this wave's 16 rows
    const int nB = 2 * jB + 1 + (wid >> 2);
    const int nkt = 2 * jB + 2;              // block trip count (>= 18)

    const u16* Qb = Qg + (size_t)bh * TT * DKK;
    const u16* Kb = Kg + (size_t)bh * TT * DKK;
    const u16* Vb = Vtg + (size_t)bh * DKK * TT;

    bf16x8 qfA[2], qfB[2];
    load_qfrag16(Qb, qbaseA, l15, l4, qfA);
    load_qfrag16(Qb, qbaseB, l15, l4, qfB);

    // ones B-fragment for the row-sum MFMA
    bf16x8 onef;
    {
        union { bf16x8 v; u16 h[8]; } o;
#pragma unroll
        for (int e = 0; e < 8; e++) o.h[e] = 0x3F80;  // bf16 1.0
        onef = o.v;
    }

    f32x4 accA[4], accB[4], laccA, laccB;
    const f32x4 z4 = {0.f, 0.f, 0.f, 0.f};
#pragma unroll
    for (int j = 0; j < 4; j++) { accA[j] = z4; accB[j] = z4; }
    laccA = z4; laccB = z4;

    char* Pw = reinterpret_cast<char*>(&Pld[wid][0]);

    // prologue: 2 tiles in flight
    stage_kv(Kb, Vb, Kld[0], Vld[0], 0, tid, wid);
    stage_kv(Kb, Vb, Kld[1], Vld[1], 1, tid, wid);

    for (int kt = 0; kt < nkt; kt++) {
        if (kt + 2 < nkt) {
            stage_kv(Kb, Vb, Kld[(kt + 2) & 3], Vld[(kt + 2) & 3], kt + 2, tid, wid);
            asm volatile("s_waitcnt vmcnt(4)" ::: "memory");  // tiles kt+1,kt+2 in flight
        } else if (kt + 1 < nkt) {
            asm volatile("s_waitcnt vmcnt(2)" ::: "memory");  // tile kt+1 in flight
        } else {
            asm volatile("s_waitcnt vmcnt(0)" ::: "memory");
        }
        __syncthreads();  // single barrier per tile

        const char* Kl = reinterpret_cast<const char*>(Kld[kt & 3]);
        const char* Vl = reinterpret_cast<const char*>(Vld[kt & 3]);

        if (kt < nA)
            attn_side(qfA, accA, laccA, Kl, Vl, Pw, onef, l15, l4, kt == nA - 1, kt, qbaseA);
        if (kt < nB)
            attn_side(qfB, accB, laccB, Kl, Vl, Pw, onef, l15, l4, kt == nB - 1, kt, qbaseB);
    }

    const int b = bh >> 4, h = bh & 15;
    write_ctx16(ctx, b, h, qbaseA, l15, l4, accA, laccA);
    write_ctx16(ctx, b, h, qbaseB, l15, l4, accB, laccB);
}

// ---------------------------------------------------------------- launch
extern "C" void kernel_launch(void* const* d_in, const int* in_sizes, int n_in,
                              void* d_out, int out_size, void* d_ws, size_t ws_size,
                              hipStream_t stream) {
    const float* x = (const float*)d_in[0];
    const float* Wq = (const float*)d_in[1];
    const float* Wk = (const float*)d_in[2];
    const float* Wv = (const float*)d_in[3];
    const float* Wo = (const float*)d_in[4];

    const int nX = BB * TT * DD;        // 8388608
    const int nW = DD * DD;             // 1048576
    const int nQ = BB * HH * TT * DKK;  // 8388608

    u16* xb = (u16*)d_ws;
    u16* wqb = xb + nX;     // wq|wk|wv|wo contiguous
    u16* wkb = wqb + nW;
    u16* wvb = wkb + nW;
    u16* wob = wvb + nW;
    u16* Qb = wob + nW;
    u16* Kb = Qb + nQ;
    u16* Vtb = Kb + nQ;
    u16* ctxb = Vtb + nQ;

    cast_all<<<dim3(1024, 5), 256, 0, stream>>>(x, Wq, Wk, Wv, Wo, xb, wqb, nX, nW);

    gemm_qkv<<<dim3((BB * TT) / 128, DD / 128, 3), 256, 0, stream>>>(xb, wqb, wkb, wvb, Qb, Kb, Vtb);

    attn_fwd<<<dim3(64, 8), 512, 0, stream>>>(Qb, Kb, Vtb, ctxb);

    gemm_out<<<dim3((BB * TT) / 128, DD / 128), 256, 0, stream>>>(ctxb, wob, (float*)d_out);
}